// Round 1
// baseline (392.251 us; speedup 1.0000x reference)
//
#include <hip/hip_runtime.h>
#include <hip/hip_bf16.h>

// Problem constants (match reference)
#define NN 100000          // nodes
#define EE 1000000         // edges
#define FDIM 64            // in = out = 64
#define NREL 16
#define NBASE 8
#define HN (NN * FDIM)     // 6,400,000 floats per output tensor
#define H4 (HN / 4)        // 1,600,000 float4
#define WSZ (NREL * FDIM * FDIM)  // 65536 floats = 256 KB
#define GX 96              // blocks per rel in edge kernel (96*16=1536 blocks, 6144 waves)

__global__ void zero_counts_kernel(int* counts) {
    if (threadIdx.x < NREL) counts[threadIdx.x] = 0;
}

// W (as viewed [R,IN,OUT]) is the flat buffer of M[i,r,o] = sum_b w_comp[r,b] *
// weight_flat[i*512 + b*64 + o], M laid out [IN, R, OUT].
__global__ void compute_w_kernel(const float* __restrict__ weight,
                                 const float* __restrict__ w_comp,
                                 float* __restrict__ W) {
    int q = blockIdx.x * blockDim.x + threadIdx.x;
    if (q >= WSZ) return;
    int i = q >> 10;          // q / (R*OUT)
    int r = (q >> 6) & 15;    // (q / OUT) % R
    int o = q & 63;           // q % OUT
    float acc = 0.f;
#pragma unroll
    for (int b = 0; b < NBASE; ++b)
        acc = fmaf(w_comp[r * NBASE + b], weight[i * 512 + b * 64 + o], acc);
    W[q] = acc;
}

// out[0:HN) = relu(h); out[HN:2*HN) = 0 (h2 accumulator; d_out is poisoned 0xAA)
__global__ void relu_zero_kernel(const float4* __restrict__ h4,
                                 float4* __restrict__ out4) {
    int i = blockIdx.x * blockDim.x + threadIdx.x;
    if (i < H4) {
        float4 v = h4[i];
        v.x = fmaxf(v.x, 0.f); v.y = fmaxf(v.y, 0.f);
        v.z = fmaxf(v.z, 0.f); v.w = fmaxf(v.w, 0.f);
        out4[i] = v;
        out4[H4 + i] = make_float4(0.f, 0.f, 0.f, 0.f);
    }
}

__global__ void hist_kernel(const int* __restrict__ rel, int* __restrict__ counts) {
    __shared__ int lc[NREL];
    if (threadIdx.x < NREL) lc[threadIdx.x] = 0;
    __syncthreads();
    int stride = gridDim.x * blockDim.x;
    for (int i = blockIdx.x * blockDim.x + threadIdx.x; i < EE; i += stride)
        atomicAdd(&lc[rel[i]], 1);
    __syncthreads();
    if (threadIdx.x < NREL && lc[threadIdx.x] > 0)
        atomicAdd(&counts[threadIdx.x], lc[threadIdx.x]);
}

__global__ void scan_kernel(const int* __restrict__ counts,
                            int* __restrict__ offsets, int* __restrict__ cursors) {
    if (threadIdx.x == 0 && blockIdx.x == 0) {
        int acc = 0;
        for (int r = 0; r < NREL; ++r) { offsets[r] = acc; cursors[r] = acc; acc += counts[r]; }
        offsets[NREL] = acc;
    }
}

// Counting-sort edges by rel; store packed (src,dst) so hot loop has no indirection.
__global__ void scatter_kernel(const int* __restrict__ rel, const int* __restrict__ src,
                               const int* __restrict__ dst, int* __restrict__ cursors,
                               int* __restrict__ src_bin, int* __restrict__ dst_bin) {
    __shared__ int lhist[NREL];
    __shared__ int lbase[NREL];
    int i = blockIdx.x * blockDim.x + threadIdx.x;
    if (threadIdx.x < NREL) lhist[threadIdx.x] = 0;
    __syncthreads();
    int r = 0, rank = 0;
    if (i < EE) { r = rel[i]; rank = atomicAdd(&lhist[r], 1); }
    __syncthreads();
    if (threadIdx.x < NREL && lhist[threadIdx.x] > 0)
        lbase[threadIdx.x] = atomicAdd(&cursors[threadIdx.x], lhist[threadIdx.x]);
    __syncthreads();
    if (i < EE) {
        int pos = lbase[r] + rank;
        src_bin[pos] = src[i];
        dst_bin[pos] = dst[i];
    }
}

// One wave per edge batch; wave's rel is fixed by blockIdx.y. Lane o keeps
// W[rel][:,o] in 64 VGPRs; h row is wave-uniform -> readfirstlane forces s_load
// broadcast; inner loop is v_fmac(vdst, sgpr, vgpr). Scatter via HW fp32 atomic.
__global__ __launch_bounds__(256) void edge_kernel(
    const int* __restrict__ offsets, const int* __restrict__ src_bin,
    const int* __restrict__ dst_bin, const float* __restrict__ h,
    const float* __restrict__ W, float* __restrict__ h2) {
    const int rel = blockIdx.y;
    const int lane = threadIdx.x & 63;
    const int start = offsets[rel];
    const int end = offsets[rel + 1];

    float wcol[FDIM];
    const float* wbase = W + rel * 4096 + lane;
#pragma unroll
    for (int d = 0; d < FDIM; ++d) wcol[d] = wbase[d * 64];

    const int nw = GX * 4;                       // waves per rel
    const int wave = blockIdx.x * 4 + (threadIdx.x >> 6);
    const int cnt = end - start;
    const int per = (cnt + nw - 1) / nw;         // contiguous chunk per wave (scalar-$ locality)
    int i0 = start + wave * per;
    int i1 = i0 + per; if (i1 > end) i1 = end;

    for (int i = i0; i < i1; ++i) {
        int s  = __builtin_amdgcn_readfirstlane(src_bin[i]);
        int dv = __builtin_amdgcn_readfirstlane(dst_bin[i]);
        const float* __restrict__ hrow = h + (size_t)s * FDIM;
        float a0 = 0.f, a1 = 0.f, a2 = 0.f, a3 = 0.f;
#pragma unroll
        for (int d = 0; d < FDIM; d += 4) {      // 4 chains to break fmac latency
            a0 = fmaf(hrow[d],     wcol[d],     a0);
            a1 = fmaf(hrow[d + 1], wcol[d + 1], a1);
            a2 = fmaf(hrow[d + 2], wcol[d + 2], a2);
            a3 = fmaf(hrow[d + 3], wcol[d + 3], a3);
        }
        float acc = (a0 + a1) + (a2 + a3);
        unsafeAtomicAdd(&h2[(size_t)dv * FDIM + lane], acc);
    }
}

extern "C" void kernel_launch(void* const* d_in, const int* in_sizes, int n_in,
                              void* d_out, int out_size, void* d_ws, size_t ws_size,
                              hipStream_t stream) {
    const float* h      = (const float*)d_in[0];   // [N,64]
    const float* weight = (const float*)d_in[1];   // [B,64,64] flat
    const float* w_comp = (const float*)d_in[2];   // [R,B]
    const int*   src    = (const int*)d_in[3];
    const int*   dst    = (const int*)d_in[4];
    const int*   rel    = (const int*)d_in[5];

    float* out_hnew = (float*)d_out;               // [N,64] relu(h)
    float* out_h2   = out_hnew + HN;               // [N,64] aggregated

    // Workspace layout
    float* W       = (float*)d_ws;                           // 256 KB
    int*   meta    = (int*)((char*)d_ws + WSZ * 4);          // counts[16], offsets[17], cursors[16]
    int*   counts  = meta;
    int*   offsets = meta + 16;
    int*   cursors = meta + 33;
    int*   src_bin = (int*)((char*)d_ws + WSZ * 4 + 256);    // 4 MB
    int*   dst_bin = src_bin + EE;                           // 4 MB

    hipLaunchKernelGGL(zero_counts_kernel, dim3(1), dim3(64), 0, stream, counts);
    hipLaunchKernelGGL(compute_w_kernel, dim3(WSZ / 256), dim3(256), 0, stream,
                       weight, w_comp, W);
    hipLaunchKernelGGL(relu_zero_kernel, dim3((H4 + 255) / 256), dim3(256), 0, stream,
                       (const float4*)h, (float4*)out_hnew);
    hipLaunchKernelGGL(hist_kernel, dim3(1024), dim3(256), 0, stream, rel, counts);
    hipLaunchKernelGGL(scan_kernel, dim3(1), dim3(64), 0, stream, counts, offsets, cursors);
    hipLaunchKernelGGL(scatter_kernel, dim3((EE + 255) / 256), dim3(256), 0, stream,
                       rel, src, dst, cursors, src_bin, dst_bin);
    hipLaunchKernelGGL(edge_kernel, dim3(GX, NREL), dim3(256), 0, stream,
                       offsets, src_bin, dst_bin, h, W, out_h2);
}

// Round 3
// 374.584 us; speedup vs baseline: 1.0472x; 1.0472x over previous
//
#include <hip/hip_runtime.h>
#include <hip/hip_bf16.h>

// Problem constants (match reference)
#define NN 100000
#define EE 1000000
#define FDIM 64
#define NREL 16
#define NBASE 8
#define HN (NN * FDIM)
#define H4 (HN / 4)
#define WSZ (NREL * FDIM * FDIM)   // 65536 elements
#define EGX 128                    // blocks per rel in edge kernel

typedef __attribute__((ext_vector_type(8))) short short8;
typedef __attribute__((ext_vector_type(4))) float f32x4;

static __device__ __forceinline__ ushort f2bf(float f) {
    __hip_bfloat16 b = __float2bfloat16(f);
    return *(ushort*)&b;
}

// True rel-weight under the reference's REINTERPRETING views:
//   W[r][d][o] = M_flat[r*4096 + d*64 + o]   (M is the [IN,R,OUT] einsum result)
//             = sum_b w_comp[d&15, b] * weight[(4r + (d>>4))*512 + b*64 + o]
// (Verified symbolically identical to round 1's passing flat indexing.)
// WT stores it TRANSPOSED as [r][o][d] so MFMA B-fragments are contiguous
// 16B loads along k=d. Also zeroes the rel-histogram counts (block 0).
__global__ void compute_wt_kernel(const float* __restrict__ weight,
                                  const float* __restrict__ w_comp,
                                  ushort* __restrict__ WT, int* __restrict__ counts) {
    int q = blockIdx.x * blockDim.x + threadIdx.x;
    if (blockIdx.x == 0 && threadIdx.x < NREL) counts[threadIdx.x] = 0;
    if (q >= WSZ) return;
    int r = q >> 12;          // q / 4096
    int o = (q >> 6) & 63;    // output col
    int d = q & 63;           // input dim (k)
    const float* wc = w_comp + (d & 15) * NBASE;
    const float* wv = weight + (size_t)(4 * r + (d >> 4)) * 512 + o;
    float acc = 0.f;
#pragma unroll
    for (int b = 0; b < NBASE; ++b)
        acc = fmaf(wc[b], wv[b * 64], acc);
    WT[q] = f2bf(acc);
}

// out[0:HN) = relu(h) fp32 (exact); out[HN:2HN) = 0 (h2 accumulator);
// hb = bf16 copy of h for the MFMA gather.
__global__ void relu_zero_cvt_kernel(const float4* __restrict__ h4,
                                     float4* __restrict__ out4,
                                     ushort2* __restrict__ hb2) {
    int i = blockIdx.x * blockDim.x + threadIdx.x;
    if (i < H4) {
        float4 v = h4[i];
        ushort2 lo, hi;
        lo.x = f2bf(v.x); lo.y = f2bf(v.y);
        hi.x = f2bf(v.z); hi.y = f2bf(v.w);
        hb2[2 * i] = lo;
        hb2[2 * i + 1] = hi;
        v.x = fmaxf(v.x, 0.f); v.y = fmaxf(v.y, 0.f);
        v.z = fmaxf(v.z, 0.f); v.w = fmaxf(v.w, 0.f);
        out4[i] = v;
        out4[H4 + i] = make_float4(0.f, 0.f, 0.f, 0.f);
    }
}

__global__ void hist_kernel(const int* __restrict__ rel, int* __restrict__ counts) {
    __shared__ int lc[NREL];
    if (threadIdx.x < NREL) lc[threadIdx.x] = 0;
    __syncthreads();
    int stride = gridDim.x * blockDim.x;
    for (int i = blockIdx.x * blockDim.x + threadIdx.x; i < EE; i += stride)
        atomicAdd(&lc[rel[i]], 1);
    __syncthreads();
    if (threadIdx.x < NREL && lc[threadIdx.x] > 0)
        atomicAdd(&counts[threadIdx.x], lc[threadIdx.x]);
}

__global__ void scan_kernel(const int* __restrict__ counts,
                            int* __restrict__ offsets, int* __restrict__ cursors) {
    if (threadIdx.x == 0 && blockIdx.x == 0) {
        int acc = 0;
        for (int r = 0; r < NREL; ++r) { offsets[r] = acc; cursors[r] = acc; acc += counts[r]; }
        offsets[NREL] = acc;
    }
}

// Counting-sort edges by rel; store (src,dst) packed per bin.
__global__ void scatter_kernel(const int* __restrict__ rel, const int* __restrict__ src,
                               const int* __restrict__ dst, int* __restrict__ cursors,
                               int* __restrict__ src_bin, int* __restrict__ dst_bin) {
    __shared__ int lhist[NREL];
    __shared__ int lbase[NREL];
    int i = blockIdx.x * blockDim.x + threadIdx.x;
    if (threadIdx.x < NREL) lhist[threadIdx.x] = 0;
    __syncthreads();
    int r = 0, rank = 0;
    if (i < EE) { r = rel[i]; rank = atomicAdd(&lhist[r], 1); }
    __syncthreads();
    if (threadIdx.x < NREL && lhist[threadIdx.x] > 0)
        lbase[threadIdx.x] = atomicAdd(&cursors[threadIdx.x], lhist[threadIdx.x]);
    __syncthreads();
    if (i < EE) {
        int pos = lbase[r] + rank;
        src_bin[pos] = src[i];
        dst_bin[pos] = dst[i];
    }
}

// MFMA edge kernel: one wave = batches of 16 edges of a single rel.
// A (16 edges x K=64, bf16 gathered rows), B = WT[rel] in 8 frags (32 VGPRs),
// D = 16x64 messages in fp32, scattered with HW fp32 atomics.
// Layouts (HW-verified): A: m=lane&15, k=quad*8+j; B: n=lane&15, k=quad*8+j;
// C/D: col=lane&15, row=quad*4+reg. Any per-lane k-permutation cancels
// between A and B since both pack contiguous k.
__global__ __launch_bounds__(256) void edge_mfma_kernel(
    const int* __restrict__ offsets, const int* __restrict__ src_bin,
    const int* __restrict__ dst_bin, const ushort* __restrict__ hb,
    const ushort* __restrict__ WT, float* __restrict__ h2) {
    const int rel  = blockIdx.y;
    const int lane = threadIdx.x & 63;
    const int quad = lane >> 4;
    const int l15  = lane & 15;
    const int start = offsets[rel];
    const int end   = offsets[rel + 1];
    const int cnt   = end - start;
    if (cnt <= 0) return;

    // B fragments: Bf[s][t] holds WT[rel][n=16t+l15][k=32s+8q .. +8]
    const short8* wt = (const short8*)(WT + rel * 4096);
    short8 Bf[2][4];
#pragma unroll
    for (int t = 0; t < 4; ++t) {
#pragma unroll
        for (int s = 0; s < 2; ++s)
            Bf[s][t] = wt[((t * 16 + l15) << 3) + (s << 2) + quad];
    }

    const int nw   = EGX * 4;                       // waves per rel
    const int wave = blockIdx.x * 4 + (threadIdx.x >> 6);
    const int nb   = (cnt + 15) >> 4;               // 16-edge batches in bin
    const int per  = (nb + nw - 1) / nw;
    int b0 = wave * per;
    int b1 = b0 + per; if (b1 > nb) b1 = nb;

    const int quad4 = quad * 4;

    for (int b = b0; b < b1; ++b) {
        const int base = start + (b << 4);
        // ---- gather A (16 rows x 64 bf16) ----
        int ei = base + l15; if (ei >= end) ei = end - 1;   // clamp tail (discarded later)
        int s0 = src_bin[ei];
        const short8* ar = (const short8*)(hb + (size_t)s0 * FDIM);
        short8 A0 = ar[quad];
        short8 A1 = ar[4 + quad];

        // ---- 8 MFMAs: 4 N-tiles x 2 K-steps ----
        f32x4 acc[4];
#pragma unroll
        for (int t = 0; t < 4; ++t) acc[t] = (f32x4){0.f, 0.f, 0.f, 0.f};
#pragma unroll
        for (int t = 0; t < 4; ++t) {
            acc[t] = __builtin_amdgcn_mfma_f32_16x16x32_bf16(A0, Bf[0][t], acc[t], 0, 0, 0);
            acc[t] = __builtin_amdgcn_mfma_f32_16x16x32_bf16(A1, Bf[1][t], acc[t], 0, 0, 0);
        }

        // ---- scatter: lane holds rows m=quad4+reg, col o=16t+l15 ----
#pragma unroll
        for (int r = 0; r < 4; ++r) {
            int em = base + quad4 + r;
            if (em < end) {
                int dv = dst_bin[em];
                float* p = h2 + (size_t)dv * FDIM + l15;
                unsafeAtomicAdd(p,      acc[0][r]);
                unsafeAtomicAdd(p + 16, acc[1][r]);
                unsafeAtomicAdd(p + 32, acc[2][r]);
                unsafeAtomicAdd(p + 48, acc[3][r]);
            }
        }
    }
}

extern "C" void kernel_launch(void* const* d_in, const int* in_sizes, int n_in,
                              void* d_out, int out_size, void* d_ws, size_t ws_size,
                              hipStream_t stream) {
    const float* h      = (const float*)d_in[0];
    const float* weight = (const float*)d_in[1];
    const float* w_comp = (const float*)d_in[2];
    const int*   src    = (const int*)d_in[3];
    const int*   dst    = (const int*)d_in[4];
    const int*   rel    = (const int*)d_in[5];

    float* out_hnew = (float*)d_out;
    float* out_h2   = out_hnew + HN;

    // Workspace layout (byte offsets, all 16B aligned)
    char* ws = (char*)d_ws;
    ushort* WT      = (ushort*)ws;                         // 128 KB  [0, 0x20000)
    int*    meta    = (int*)(ws + 0x20000);                // counts16/offsets17/cursors16
    int*    counts  = meta;
    int*    offsets = meta + 16;
    int*    cursors = meta + 33;
    int*    src_bin = (int*)(ws + 0x20400);                // 4 MB
    int*    dst_bin = (int*)(ws + 0x20400 + 4 * EE);       // 4 MB
    ushort* hb      = (ushort*)(ws + 0x20400 + 8 * EE);    // 12.8 MB

    hipLaunchKernelGGL(compute_wt_kernel, dim3(WSZ / 256), dim3(256), 0, stream,
                       weight, w_comp, WT, counts);
    hipLaunchKernelGGL(relu_zero_cvt_kernel, dim3((H4 + 255) / 256), dim3(256), 0, stream,
                       (const float4*)h, (float4*)out_hnew, (ushort2*)hb);
    hipLaunchKernelGGL(hist_kernel, dim3(1024), dim3(256), 0, stream, rel, counts);
    hipLaunchKernelGGL(scan_kernel, dim3(1), dim3(64), 0, stream, counts, offsets, cursors);
    hipLaunchKernelGGL(scatter_kernel, dim3((EE + 255) / 256), dim3(256), 0, stream,
                       rel, src, dst, cursors, src_bin, dst_bin);
    hipLaunchKernelGGL(edge_mfma_kernel, dim3(EGX, NREL), dim3(256), 0, stream,
                       offsets, src_bin, dst_bin, hb, WT, out_h2);
}